// Round 11
// baseline (913.110 us; speedup 1.0000x reference)
//
#include <hip/hip_runtime.h>
#include <hip/hip_fp16.h>
#include <stdint.h>

#define NN      100000
#define EE      1600000
#define NFEATC  128
#define NHIDC   32
#define NHEADSC 8
#define NCLASSC 40
#define FDIM    256     // NHEADS*NHID
#define NBLK    ((NN+255)/256)   // 391

typedef unsigned short u16;
typedef __attribute__((ext_vector_type(8))) short bf16x8;
typedef __attribute__((ext_vector_type(4))) float f32x4;

__device__ __forceinline__ float b2f(u16 u){ union{uint32_t i; float f;} v; v.i=((uint32_t)u)<<16; return v.f; }
__device__ __forceinline__ u16 f2b(float f){ union{float f; uint32_t i;} v; v.f=f; uint32_t x=v.i; return (u16)((x + 0x7FFFu + ((x>>16)&1u))>>16); }
__device__ __forceinline__ float lrelu(float e){ return e > 0.f ? e : 0.2f*e; }

// ---------------- W transpose+cast: Wt[c][k] = bf16(W[head][k][hid]) -------
__global__ __launch_bounds__(256) void k_transposeW(const float* __restrict__ W, u16* __restrict__ Wt){
  int i = blockIdx.x*256 + threadIdx.x;
  if (i >= FDIM*NFEATC) return;
  int c = i >> 7, k = i & 127;
  int head = c >> 5, hid = c & 31;
  Wt[c*NFEATC + k] = f2b(W[head*(NFEATC*NHIDC) + k*NHIDC + hid]);
}

// ---------------- GEMM1 via MFMA: h0 = x @ W  (fp16 out) -------------------
__global__ __launch_bounds__(256) void k_gemm1_mfma(const float* __restrict__ x, const u16* __restrict__ Wt,
                                                    __half* __restrict__ h0){
  int w = threadIdx.x >> 6, lane = threadIdx.x & 63;
  int nt = blockIdx.x;
  int m = lane & 15, q = lane >> 4;
  int row = nt*16 + m;
  int c0 = w*64;
  const float* xrow = x + (size_t)row*NFEATC;
  f32x4 acc0 = {0.f,0.f,0.f,0.f}, acc1 = {0.f,0.f,0.f,0.f};
  f32x4 acc2 = {0.f,0.f,0.f,0.f}, acc3 = {0.f,0.f,0.f,0.f};
  #pragma unroll
  for (int kk=0; kk<NFEATC; kk+=32){
    int ko = kk + q*8;
    float4 xa = *(const float4*)(xrow + ko);
    float4 xb = *(const float4*)(xrow + ko + 4);
    bf16x8 a;
    a[0]=(short)f2b(xa.x); a[1]=(short)f2b(xa.y); a[2]=(short)f2b(xa.z); a[3]=(short)f2b(xa.w);
    a[4]=(short)f2b(xb.x); a[5]=(short)f2b(xb.y); a[6]=(short)f2b(xb.z); a[7]=(short)f2b(xb.w);
    bf16x8 b0 = *(const bf16x8*)(Wt + (size_t)(c0 +  0 + m)*NFEATC + ko);
    bf16x8 b1 = *(const bf16x8*)(Wt + (size_t)(c0 + 16 + m)*NFEATC + ko);
    bf16x8 b2 = *(const bf16x8*)(Wt + (size_t)(c0 + 32 + m)*NFEATC + ko);
    bf16x8 b3 = *(const bf16x8*)(Wt + (size_t)(c0 + 48 + m)*NFEATC + ko);
    acc0 = __builtin_amdgcn_mfma_f32_16x16x32_bf16(a, b0, acc0, 0,0,0);
    acc1 = __builtin_amdgcn_mfma_f32_16x16x32_bf16(a, b1, acc1, 0,0,0);
    acc2 = __builtin_amdgcn_mfma_f32_16x16x32_bf16(a, b2, acc2, 0,0,0);
    acc3 = __builtin_amdgcn_mfma_f32_16x16x32_bf16(a, b3, acc3, 0,0,0);
  }
  #pragma unroll
  for (int r=0; r<4; r++){
    size_t base = (size_t)(nt*16 + q*4 + r)*FDIM + c0 + m;
    h0[base +  0] = __float2half(acc0[r]);
    h0[base + 16] = __float2half(acc1[r]);
    h0[base + 32] = __float2half(acc2[r]);
    h0[base + 48] = __float2half(acc3[r]);
  }
}

// ---------------- s,t per (node,head), fp16 --------------------------------
__global__ __launch_bounds__(256) void k_st(const __half* __restrict__ h0, const float* __restrict__ a_src,
                                            const float* __restrict__ a_dst, __half* __restrict__ s,
                                            __half* __restrict__ t_){
  int i = blockIdx.x*256 + threadIdx.x;
  if (i >= NN*NHEADSC) return;
  int n = i>>3, head = i&7;
  const __half* hp = h0 + (size_t)n*FDIM + head*NHIDC;
  const float* ap = a_src + head*NHIDC;
  const float* bp = a_dst + head*NHIDC;
  float ss=0.f, tt=0.f;
  #pragma unroll
  for (int j=0;j<NHIDC;j++){
    float h = __half2float(hp[j]);
    ss = fmaf(h, ap[j], ss); tt = fmaf(h, bp[j], tt);
  }
  s[i]=__float2half(ss); t_[i]=__float2half(tt);
}

// ---------------- CSR build ------------------------------------------------
__global__ __launch_bounds__(256) void k_zero(int* __restrict__ p, int n){
  int i = blockIdx.x*256 + threadIdx.x;
  if (i < n) p[i] = 0;
}
__global__ __launch_bounds__(256) void k_count(const int* __restrict__ dst, int* __restrict__ counts){
  int e = blockIdx.x*256 + threadIdx.x;
  if (e < EE) atomicAdd(&counts[dst[e]], 1);
}
__global__ __launch_bounds__(256) void k_blocksum(const int* __restrict__ counts, int* __restrict__ bsum){
  __shared__ int wsum[4];
  int b = blockIdx.x, t = threadIdx.x;
  int i = b*256 + t;
  int v = (i < NN) ? counts[i] : 0;
  #pragma unroll
  for (int off=32; off; off>>=1) v += __shfl_xor(v, off);
  if ((t & 63) == 0) wsum[t>>6] = v;
  __syncthreads();
  if (t == 0) bsum[b] = wsum[0]+wsum[1]+wsum[2]+wsum[3];
}
__global__ __launch_bounds__(512) void k_scan_bsum(const int* __restrict__ bsum, int* __restrict__ boff){
  __shared__ int lds[512];
  int t = threadIdx.x;
  int v = (t < NBLK) ? bsum[t] : 0;
  lds[t] = v; __syncthreads();
  for (int off=1; off<512; off<<=1){
    int u = (t>=off) ? lds[t-off] : 0;
    __syncthreads();
    lds[t] += u;
    __syncthreads();
  }
  if (t < NBLK) boff[t] = lds[t] - v;
}
__global__ __launch_bounds__(256) void k_scan_final(const int* __restrict__ counts, const int* __restrict__ boff,
                                                    int* __restrict__ row_start){
  __shared__ int lds[256];
  int b = blockIdx.x, t = threadIdx.x;
  int i = b*256 + t;
  int v = (i < NN) ? counts[i] : 0;
  lds[t] = v; __syncthreads();
  for (int off=1; off<256; off<<=1){
    int u = (t>=off) ? lds[t-off] : 0;
    __syncthreads();
    lds[t] += u;
    __syncthreads();
  }
  if (i < NN) row_start[i] = boff[b] + lds[t] - v;
  if (b == 0 && t == 0) row_start[NN] = EE;
}
__global__ __launch_bounds__(256) void k_scatter(const int* __restrict__ src, const int* __restrict__ dst,
                                                 const int* __restrict__ row_start, int* __restrict__ fill,
                                                 int* __restrict__ csr_src){
  int e = blockIdx.x*256 + threadIdx.x;
  if (e >= EE) return;
  int d = dst[e];
  int pos = row_start[d] + atomicAdd(&fill[d], 1);
  csr_src[pos] = src[e];
}

// ---------------- attention, all 8 heads: p_all (fp16) + 1/denom (fp16) ----
__global__ __launch_bounds__(256) void k_att(const __half* __restrict__ s, const __half* __restrict__ t_,
                                             const int* __restrict__ row_start, const int* __restrict__ csr_src,
                                             __half* __restrict__ p_all, __half* __restrict__ scale){
  int i = blockIdx.x*256 + threadIdx.x;
  if (i >= NN*NHEADSC) return;
  int n = i>>3, head = i&7;
  int beg = row_start[n], end = row_start[n+1];
  float tn = __half2float(t_[i]);
  float d0=0.f,d1=0.f,d2=0.f,d3=0.f;
  int pos = beg;
  for (; pos+4<=end; pos+=4){
    int u0=csr_src[pos], u1=csr_src[pos+1], u2=csr_src[pos+2], u3=csr_src[pos+3];
    float e0=lrelu(__half2float(s[u0*NHEADSC+head])+tn);
    float e1=lrelu(__half2float(s[u1*NHEADSC+head])+tn);
    float e2=lrelu(__half2float(s[u2*NHEADSC+head])+tn);
    float e3=lrelu(__half2float(s[u3*NHEADSC+head])+tn);
    __half p0=__float2half(__expf(e0)), p1=__float2half(__expf(e1));
    __half p2=__float2half(__expf(e2)), p3=__float2half(__expf(e3));
    p_all[(size_t)(pos+0)*NHEADSC+head]=p0;
    p_all[(size_t)(pos+1)*NHEADSC+head]=p1;
    p_all[(size_t)(pos+2)*NHEADSC+head]=p2;
    p_all[(size_t)(pos+3)*NHEADSC+head]=p3;
    d0+=__half2float(p0); d1+=__half2float(p1); d2+=__half2float(p2); d3+=__half2float(p3);
  }
  for (; pos<end; pos++){
    int u = csr_src[pos];
    float e = lrelu(__half2float(s[u*NHEADSC+head])+tn);
    __half pb = __float2half(__expf(e));
    p_all[(size_t)pos*NHEADSC+head]=pb;
    d0 += __half2float(pb);
  }
  scale[i] = __float2half(1.0f/(((d0+d1)+(d2+d3)) + 1e-16f));
}

// ---------------- hop1 full row: wave/node, 4 ch/lane, pk_fma, unroll 8 ----
__global__ __launch_bounds__(256) void k_hop1(const __half* __restrict__ h0, const __half* __restrict__ p_all,
                                              const __half* __restrict__ scale, const int* __restrict__ row_start,
                                              const int* __restrict__ csr_src, __half* __restrict__ featA){
  int wv = threadIdx.x >> 6, l = threadIdx.x & 63;
  int n = blockIdx.x*4 + wv;
  int head = l >> 3;
  int cg = 4*l;
  float sc_ = __half2float(scale[n*NHEADSC + head]);
  int beg = row_start[n], end = row_start[n+1];
  __half2 z = __float2half2_rn(0.f);
  __half2 acc[8][2];
  #pragma unroll
  for (int j=0;j<8;j++){ acc[j][0]=z; acc[j][1]=z; }
  int pos = beg;
  for (; pos+8<=end; pos+=8){
    #pragma unroll
    for (int j=0;j<8;j++){
      int u = csr_src[pos+j];
      __half2 pp = __half2half2(p_all[(size_t)(pos+j)*NHEADSC + head]);
      const __half2* g = (const __half2*)(h0 + (size_t)u*FDIM + cg);
      acc[j][0] = __hfma2(pp, g[0], acc[j][0]);
      acc[j][1] = __hfma2(pp, g[1], acc[j][1]);
    }
  }
  for (; pos<end; pos++){
    int u = csr_src[pos];
    __half2 pp = __half2half2(p_all[(size_t)pos*NHEADSC + head]);
    const __half2* g = (const __half2*)(h0 + (size_t)u*FDIM + cg);
    acc[0][0] = __hfma2(pp, g[0], acc[0][0]);
    acc[0][1] = __hfma2(pp, g[1], acc[0][1]);
  }
  float ax=0.f, ay=0.f, az=0.f, aw=0.f;
  #pragma unroll
  for (int j=0;j<8;j++){
    float2 f0 = __half22float2(acc[j][0]);
    float2 f1 = __half22float2(acc[j][1]);
    ax+=f0.x; ay+=f0.y; az+=f1.x; aw+=f1.y;
  }
  const __half2* hu = (const __half2*)(h0 + (size_t)n*FDIM + cg);
  float2 h0v = __half22float2(hu[0]), h1v = __half22float2(hu[1]);
  __half2 o0 = __floats2half2_rn(0.9f*sc_*ax + 0.1f*h0v.x, 0.9f*sc_*ay + 0.1f*h0v.y);
  __half2 o1 = __floats2half2_rn(0.9f*sc_*az + 0.1f*h1v.x, 0.9f*sc_*aw + 0.1f*h1v.y);
  __half2* op = (__half2*)(featA + (size_t)n*FDIM + cg);
  op[0] = o0; op[1] = o1;
}

// ---------------- hop2 full row + elu + GEMM2, pk_fma, unroll 8 ------------
__global__ __launch_bounds__(256) void k_hop2(const __half* __restrict__ featA, const __half* __restrict__ h0,
                                              const __half* __restrict__ p_all, const __half* __restrict__ scale,
                                              const int* __restrict__ row_start, const int* __restrict__ csr_src,
                                              const float* __restrict__ W_out, float* __restrict__ out0){
  __shared__ float hs[4][FDIM+4];
  int wv = threadIdx.x >> 6, l = threadIdx.x & 63;
  int n = blockIdx.x*4 + wv;
  int head = l >> 3;
  int cg = 4*l;
  float sc_ = __half2float(scale[n*NHEADSC + head]);
  int beg = row_start[n], end = row_start[n+1];
  __half2 z = __float2half2_rn(0.f);
  __half2 acc[8][2];
  #pragma unroll
  for (int j=0;j<8;j++){ acc[j][0]=z; acc[j][1]=z; }
  int pos = beg;
  for (; pos+8<=end; pos+=8){
    #pragma unroll
    for (int j=0;j<8;j++){
      int u = csr_src[pos+j];
      __half2 pp = __half2half2(p_all[(size_t)(pos+j)*NHEADSC + head]);
      const __half2* g = (const __half2*)(featA + (size_t)u*FDIM + cg);
      acc[j][0] = __hfma2(pp, g[0], acc[j][0]);
      acc[j][1] = __hfma2(pp, g[1], acc[j][1]);
    }
  }
  for (; pos<end; pos++){
    int u = csr_src[pos];
    __half2 pp = __half2half2(p_all[(size_t)pos*NHEADSC + head]);
    const __half2* g = (const __half2*)(featA + (size_t)u*FDIM + cg);
    acc[0][0] = __hfma2(pp, g[0], acc[0][0]);
    acc[0][1] = __hfma2(pp, g[1], acc[0][1]);
  }
  float ax=0.f, ay=0.f, az=0.f, aw=0.f;
  #pragma unroll
  for (int j=0;j<8;j++){
    float2 f0 = __half22float2(acc[j][0]);
    float2 f1 = __half22float2(acc[j][1]);
    ax+=f0.x; ay+=f0.y; az+=f1.x; aw+=f1.y;
  }
  const __half2* hu = (const __half2*)(h0 + (size_t)n*FDIM + cg);
  float2 h0v = __half22float2(hu[0]), h1v = __half22float2(hu[1]);
  float rx = 0.9f*sc_*ax + 0.1f*h0v.x;
  float ry = 0.9f*sc_*ay + 0.1f*h0v.y;
  float rz = 0.9f*sc_*az + 0.1f*h1v.x;
  float rw = 0.9f*sc_*aw + 0.1f*h1v.y;
  hs[wv][cg  ] = rx > 0.f ? rx : (__expf(rx)-1.0f);
  hs[wv][cg+1] = ry > 0.f ? ry : (__expf(ry)-1.0f);
  hs[wv][cg+2] = rz > 0.f ? rz : (__expf(rz)-1.0f);
  hs[wv][cg+3] = rw > 0.f ? rw : (__expf(rw)-1.0f);
  __syncthreads();
  int t = threadIdx.x;
  if (t < 4*NCLASSC){
    int node = t/NCLASSC, c = t%NCLASSC;
    const float* hv = hs[node];
    const float* wp = W_out + c;
    float o = 0.f;
    #pragma unroll 8
    for (int k=0;k<FDIM;k++) o = fmaf(hv[k], wp[(size_t)k*NCLASSC], o);
    out0[(size_t)(blockIdx.x*4+node)*NCLASSC + c] = o;
  }
}

// ---------------- output-layer s,t -----------------------------------------
__global__ __launch_bounds__(256) void k_st_out(const float* __restrict__ out0, const float* __restrict__ a_s,
                                                const float* __restrict__ a_d, float* __restrict__ s,
                                                float* __restrict__ t_){
  int n = blockIdx.x*256 + threadIdx.x;
  if (n >= NN) return;
  const float* r = out0 + (size_t)n*NCLASSC;
  float ss=0.f, tt=0.f;
  for (int c=0;c<NCLASSC;c++){ float v=r[c]; ss=fmaf(v,a_s[c],ss); tt=fmaf(v,a_d[c],tt); }
  s[n]=ss; t_[n]=tt;
}

// ---------------- output-layer attention: p (fp32), unroll x4 --------------
__global__ __launch_bounds__(256) void k_att_out(const float* __restrict__ s, const float* __restrict__ t_,
                                                 const int* __restrict__ row_start, const int* __restrict__ csr_src,
                                                 float* __restrict__ p_out, float* __restrict__ scale_out){
  int n = blockIdx.x*256 + threadIdx.x;
  if (n >= NN) return;
  int beg = row_start[n], end = row_start[n+1];
  float tn = t_[n];
  float d0=0.f,d1=0.f,d2=0.f,d3=0.f;
  int pos = beg;
  for (; pos+4<=end; pos+=4){
    int u0=csr_src[pos], u1=csr_src[pos+1], u2=csr_src[pos+2], u3=csr_src[pos+3];
    float p0=__expf(lrelu(s[u0]+tn));
    float p1=__expf(lrelu(s[u1]+tn));
    float p2=__expf(lrelu(s[u2]+tn));
    float p3=__expf(lrelu(s[u3]+tn));
    p_out[pos]=p0; p_out[pos+1]=p1; p_out[pos+2]=p2; p_out[pos+3]=p3;
    d0+=p0; d1+=p1; d2+=p2; d3+=p3;
  }
  for (; pos<end; pos++){
    float p = __expf(lrelu(s[csr_src[pos]]+tn));
    p_out[pos] = p;
    d0 += p;
  }
  scale_out[n] = 1.0f/(((d0+d1)+(d2+d3)) + 1e-16f);
}

// ---------------- output-layer hop 1, unroll x4 ----------------------------
__global__ __launch_bounds__(64) void k_hop1_out(const float* __restrict__ out0, const float* __restrict__ p_out,
                                                 const float* __restrict__ scale_out, const int* __restrict__ row_start,
                                                 const int* __restrict__ csr_src, u16* __restrict__ outA){
  int n = blockIdx.x, t = threadIdx.x;
  float sc_ = scale_out[n];
  int beg = row_start[n], end = row_start[n+1];
  int tc = (t < NCLASSC) ? t : 0;
  float a0=0.f,a1=0.f,a2=0.f,a3=0.f;
  int pos = beg;
  for (; pos+4<=end; pos+=4){
    int u0=csr_src[pos], u1=csr_src[pos+1], u2=csr_src[pos+2], u3=csr_src[pos+3];
    float p0=p_out[pos], p1=p_out[pos+1], p2=p_out[pos+2], p3=p_out[pos+3];
    float f0=out0[(size_t)u0*NCLASSC+tc];
    float f1=out0[(size_t)u1*NCLASSC+tc];
    float f2=out0[(size_t)u2*NCLASSC+tc];
    float f3=out0[(size_t)u3*NCLASSC+tc];
    a0=fmaf(p0,f0,a0); a1=fmaf(p1,f1,a1); a2=fmaf(p2,f2,a2); a3=fmaf(p3,f3,a3);
  }
  for (; pos<end; pos++){
    a0=fmaf(p_out[pos], out0[(size_t)csr_src[pos]*NCLASSC+tc], a0);
  }
  if (t < NCLASSC){
    float res = 0.9f*sc_*((a0+a1)+(a2+a3)) + 0.1f*out0[(size_t)n*NCLASSC + t];
    outA[(size_t)n*NCLASSC + t] = f2b(res);
  }
}

// ---------------- output-layer hop 2 + elu + log_softmax, unroll x4 --------
__global__ __launch_bounds__(64) void k_hop2_out_final(const u16* __restrict__ outA, const float* __restrict__ out0,
                                                       const float* __restrict__ p_out, const float* __restrict__ scale_out,
                                                       const int* __restrict__ row_start, const int* __restrict__ csr_src,
                                                       float* __restrict__ out){
  int n = blockIdx.x, t = threadIdx.x;
  float sc_ = scale_out[n];
  int beg = row_start[n], end = row_start[n+1];
  int tc = (t < NCLASSC) ? t : 0;
  float a0=0.f,a1=0.f,a2=0.f,a3=0.f;
  int pos = beg;
  for (; pos+4<=end; pos+=4){
    int u0=csr_src[pos], u1=csr_src[pos+1], u2=csr_src[pos+2], u3=csr_src[pos+3];
    float p0=p_out[pos], p1=p_out[pos+1], p2=p_out[pos+2], p3=p_out[pos+3];
    float f0=b2f(outA[(size_t)u0*NCLASSC+tc]);
    float f1=b2f(outA[(size_t)u1*NCLASSC+tc]);
    float f2=b2f(outA[(size_t)u2*NCLASSC+tc]);
    float f3=b2f(outA[(size_t)u3*NCLASSC+tc]);
    a0=fmaf(p0,f0,a0); a1=fmaf(p1,f1,a1); a2=fmaf(p2,f2,a2); a3=fmaf(p3,f3,a3);
  }
  for (; pos<end; pos++){
    a0=fmaf(p_out[pos], b2f(outA[(size_t)csr_src[pos]*NCLASSC+tc]), a0);
  }
  float v = -1e30f;
  if (t < NCLASSC){
    float res = 0.9f*sc_*((a0+a1)+(a2+a3)) + 0.1f*out0[(size_t)n*NCLASSC + t];
    v = res > 0.f ? res : (__expf(res)-1.0f);
  }
  float m = v;
  #pragma unroll
  for (int off=32; off; off>>=1) m = fmaxf(m, __shfl_xor(m, off));
  float ex = (t < NCLASSC) ? __expf(v - m) : 0.f;
  float ssum = ex;
  #pragma unroll
  for (int off=32; off; off>>=1) ssum += __shfl_xor(ssum, off);
  if (t < NCLASSC) out[(size_t)n*NCLASSC + t] = v - m - __logf(ssum);
}

extern "C" void kernel_launch(void* const* d_in, const int* in_sizes, int n_in,
                              void* d_out, int out_size, void* d_ws, size_t ws_size,
                              hipStream_t stream){
  const float* x        = (const float*)d_in[0];
  const int*   ei       = (const int*)d_in[1];
  const float* W        = (const float*)d_in[2];
  const float* a_src    = (const float*)d_in[3];
  const float* a_dst    = (const float*)d_in[4];
  const float* W_out    = (const float*)d_in[5];
  const float* a_src_o  = (const float*)d_in[6];
  const float* a_dst_o  = (const float*)d_in[7];
  float* out            = (float*)d_out;
  const int* e_src = ei;
  const int* e_dst = ei + EE;

  // ---- workspace: ~156.1 MB (< 156.87 MB proven safe) ----
  char* ws = (char*)d_ws;
  size_t off = 0;
  auto alloc = [&](size_t bytes)->char*{ char* p = ws + off; off += (bytes + 255) & ~(size_t)255; return p; };

  __half* h0        = (__half*)alloc((size_t)NN*FDIM*2);      // 51.2 MB
  __half* featA     = (__half*)alloc((size_t)NN*FDIM*2);      // 51.2 MB (outA aliases phase 4)
  float*  out0      = (float*) alloc((size_t)NN*NCLASSC*4);   // 16 MB
  int*    csr_src   = (int*)   alloc((size_t)EE*4);           // 6.4 MB
  int*    row_start = (int*)   alloc((size_t)(NN+1)*4);       // 0.4 MB
  char*   regS      =          alloc((size_t)NN*NHEADSC*2*2); // 3.2 MB: s,t then phase-4 smalls
  __half* p_all     = (__half*)alloc((size_t)EE*NHEADSC*2);   // 25.6 MB (fp32 p_out aliased later)
  __half* scale     = (__half*)alloc((size_t)NN*NHEADSC*2);   // 1.6 MB
  int*    counts    = (int*)   alloc((size_t)NN*4);           // 0.4 MB
  int*    bsum      = (int*)   alloc((size_t)NBLK*4);
  int*    boff      = (int*)   alloc((size_t)NBLK*4);
  u16*    Wt        = (u16*)   alloc((size_t)FDIM*NFEATC*2);  // 64 KB

  __half* s         = (__half*)regS;                   // phase 1-3a
  __half* t_        = (__half*)(regS + (size_t)NN*NHEADSC*2);
  float*  s_out     = (float*)regS;                    // phase 4 (s,t dead)
  float*  t_out     = s_out + NN;
  float*  scale_out = t_out + NN;
  u16*    outA      = (u16*)featA;                     // phase 4 (featA dead)
  float*  p_out     = (float*)p_all;                   // phase 4 (p_all dead)

  // phase 1: feature transform (MFMA) + per-head s,t
  k_transposeW<<<(FDIM*NFEATC+255)/256, 256, 0, stream>>>(W, Wt);
  k_gemm1_mfma<<<NN/16, 256, 0, stream>>>(x, Wt, h0);
  k_st<<<(NN*NHEADSC+255)/256, 256, 0, stream>>>(h0, a_src, a_dst, s, t_);

  // phase 2: CSR build (hierarchical scan)
  k_zero<<<(NN+255)/256, 256, 0, stream>>>(counts, NN);
  k_count<<<(EE+255)/256, 256, 0, stream>>>(e_dst, counts);
  k_blocksum<<<NBLK, 256, 0, stream>>>(counts, bsum);
  k_scan_bsum<<<1, 512, 0, stream>>>(bsum, boff);
  k_scan_final<<<NBLK, 256, 0, stream>>>(counts, boff, row_start);
  k_zero<<<(NN+255)/256, 256, 0, stream>>>(counts, NN);
  k_scatter<<<(EE+255)/256, 256, 0, stream>>>(e_src, e_dst, row_start, counts, csr_src);

  // phase 3: attention pass, then full-row hop1 + hop2(+GEMM2)
  k_att<<<(NN*NHEADSC+255)/256, 256, 0, stream>>>(s, t_, row_start, csr_src, p_all, scale);
  k_hop1<<<NN/4, 256, 0, stream>>>(h0, p_all, scale, row_start, csr_src, featA);
  k_hop2<<<NN/4, 256, 0, stream>>>(featA, h0, p_all, scale, row_start, csr_src, W_out, out0);

  // phase 4: output layer (p precomputed fp32, aliased into p_all)
  k_st_out<<<(NN+255)/256, 256, 0, stream>>>(out0, a_src_o, a_dst_o, s_out, t_out);
  k_att_out<<<(NN+255)/256, 256, 0, stream>>>(s_out, t_out, row_start, csr_src, p_out, scale_out);
  k_hop1_out<<<NN, 64, 0, stream>>>(out0, p_out, scale_out, row_start, csr_src, outA);
  k_hop2_out_final<<<NN, 64, 0, stream>>>(outA, out0, p_out, scale_out, row_start, csr_src, out);
}